// Round 8
// baseline (106.458 us; speedup 1.0000x reference)
//
#include <hip/hip_runtime.h>
#include <hip/hip_bf16.h>
#include <hip/hip_fp16.h>
#include <math.h>

#define NN    2048
#define ODIM  32
#define IDIM  128
#define NEGINF (-9.0e15f)
#define LEAK   0.05f
#define LNEPS  1e-6f
#define NCHEB  10          // degree; NCHEB+1 coefficients
#define ROWS   8           // rows per block in main kernel
#define BLK    512         // threads in main kernel (8 waves)

// ws layout (floats)
#define Z_OFF   16
#define SRC_OFF (Z_OFF + NN*ODIM)
#define DST_OFF (SRC_OFF + NN)

#define WT_STRIDE 132      // IDIM(128) + 4 pad  -- rows are c=0..127! (R4 bug: 48)

// ---------------------------------------------------------------------------
// Kernel Z: z = ini @ W, src = z@a[:32], dst = z@a[32:].
// Block 0 additionally computes Chebyshev coefficients (f32) of
//   g(ts) = sum_k a[2k]*sin((te-ts)*f_k) + a[2k+1]*cos((te-ts)*f_k), ts in [0,1]
// ---------------------------------------------------------------------------
__global__ __launch_bounds__(256) void k_z(const float* __restrict__ ini,
                                           const float* __restrict__ a,
                                           const float* __restrict__ W,
                                           const float* __restrict__ bfreq,
                                           const int* __restrict__ time_end,
                                           float* __restrict__ ws)
{
    __shared__ float Wt[ODIM * WT_STRIDE];  // W^T [k][c], c=0..127, stride 132
    __shared__ float inil[8 * IDIM];        // 8 ini rows
    __shared__ float gnode[NCHEB + 1];

    const int tid  = threadIdx.x;
    const int row0 = blockIdx.x * 8;

    if (blockIdx.x == 0) {
        const float te = (float)(*time_end);
        #pragma unroll
        for (int pass = 0; pass < 2; ++pass) {
            const int idx = tid + pass * 256;
            const int j = idx >> 5, k = idx & 31;
            float term = 0.f;
            if (idx < (NCHEB + 1) * 32) {
                float u   = cosf((float)M_PI * (float)j / (float)NCHEB);
                float tsv = 0.5f * (u + 1.0f);
                float mm  = (te - tsv) * bfreq[k];
                term = a[2 * k] * sinf(mm) + a[2 * k + 1] * cosf(mm);
            }
            #pragma unroll
            for (int off = 16; off >= 1; off >>= 1)
                term += __shfl_xor(term, off, 32);
            if (k == 0 && idx < (NCHEB + 1) * 32) gnode[j] = term;
        }
        __syncthreads();
        if (tid <= NCHEB) {
            float sl = 0.f;
            for (int j = 0; j <= NCHEB; ++j) {
                float w = (j == 0 || j == NCHEB) ? 0.5f : 1.0f;
                sl += w * gnode[j] * cosf((float)M_PI * (float)(tid * j) / (float)NCHEB);
            }
            ws[tid] = ((tid == 0 || tid == NCHEB) ? (1.0f / NCHEB) : (2.0f / NCHEB)) * sl;
        }
    }

    // stage W transposed (float4 global loads) + 8 ini rows
    {
        const float4* Wv = reinterpret_cast<const float4*>(W);   // [c][k/4]
        #pragma unroll
        for (int i = 0; i < 4; ++i) {
            const int idx = tid + i * 256;          // 1024 float4 = 4096 f32
            const int c = idx >> 3, k4 = (idx & 7) * 4;
            float4 v = Wv[idx];
            Wt[(k4 + 0) * WT_STRIDE + c] = v.x;
            Wt[(k4 + 1) * WT_STRIDE + c] = v.y;
            Wt[(k4 + 2) * WT_STRIDE + c] = v.z;
            Wt[(k4 + 3) * WT_STRIDE + c] = v.w;
        }
        const float4* iv = reinterpret_cast<const float4*>(ini + row0 * IDIM);
        reinterpret_cast<float4*>(inil)[tid] = iv[tid];
    }
    __syncthreads();

    const int r = tid >> 5, k = tid & 31;
    float acc = 0.f;
    #pragma unroll
    for (int c = 0; c < IDIM; c += 4) {
        float4 wv = *reinterpret_cast<const float4*>(&Wt[k * WT_STRIDE + c]);
        float4 xv = *reinterpret_cast<const float4*>(&inil[r * IDIM + c]);
        acc = fmaf(xv.x, wv.x, acc);
        acc = fmaf(xv.y, wv.y, acc);
        acc = fmaf(xv.z, wv.z, acc);
        acc = fmaf(xv.w, wv.w, acc);
    }

    float* z   = ws + Z_OFF;
    float* src = ws + SRC_OFF;
    float* dst = ws + DST_OFF;
    z[(row0 + r) * ODIM + k] = acc;

    float sv = acc * a[k];
    float dv = acc * a[32 + k];
    #pragma unroll
    for (int off = 16; off >= 1; off >>= 1) {
        sv += __shfl_xor(sv, off, 32);
        dv += __shfl_xor(dv, off, 32);
    }
    if (k == 0) { src[row0 + r] = sv; dst[row0 + r] = dv; }
}

// Clenshaw evaluation of the Chebyshev interpolant
__device__ __forceinline__ float cheb_eval(const float cc[NCHEB + 1], float ts)
{
    float u  = fmaf(2.0f, ts, -1.0f);
    float tu = u + u;
    float b1 = 0.f, b2 = 0.f;
    #pragma unroll
    for (int k = NCHEB; k >= 1; --k) {
        float b = fmaf(tu, b1, cc[k] - b2);
        b2 = b1; b1 = b;
    }
    return fmaf(u, b1, cc[0] - b2);
}

union H4 { float2 f2; __half2 h2[2]; };

// ---------------------------------------------------------------------------
// Kernel M: 8 rows/block, 512 threads, grid 256 (1 block/CU).
// logits in registers -> exact softmax -> p(fp16) in LDS -> att@z+z -> LN.
// ---------------------------------------------------------------------------
__global__ __launch_bounds__(BLK, 2) void k_main(const int* __restrict__ adj,
                                                 const float* __restrict__ tsm,
                                                 const float* __restrict__ ws,
                                                 const float* __restrict__ gam,
                                                 const float* __restrict__ bet,
                                                 float* __restrict__ out)
{
    __shared__ __half lg[ROWS][NN];           // 32 KB normalized p (fp16)
    __shared__ float  zi[ROWS][ODIM];         // 1 KB
    __shared__ float  wredm[8][ROWS];
    __shared__ float  wreds[8][ROWS];
    __shared__ float  part[8][ROWS][ODIM];    // 8 KB

    const float* cw  = ws;
    const float* z   = ws + Z_OFF;
    const float* src = ws + SRC_OFF;
    const float* dst = ws + DST_OFF;

    const int tid  = threadIdx.x;
    const int row0 = blockIdx.x * ROWS;
    const int wid  = tid >> 6;

    float cc[NCHEB + 1];
    #pragma unroll
    for (int k = 0; k <= NCHEB; ++k) cc[k] = cw[k];

    if (tid < ROWS * ODIM) zi[tid >> 5][tid & 31] = z[row0 * ODIM + tid];

    float srcv[ROWS];
    #pragma unroll
    for (int r = 0; r < ROWS; ++r) srcv[r] = src[row0 + r];

    // ---- phase 1: one j-pass, logits in registers -------------------------
    const int j = tid * 4;                    // covers 0..2047, 4 per thread
    float4 d4 = *reinterpret_cast<const float4*>(dst + j);
    const float dv[4] = {d4.x, d4.y, d4.z, d4.w};

    float ev[ROWS][4];
    float rmax[ROWS];
    #pragma unroll
    for (int r = 0; r < ROWS; ++r) rmax[r] = NEGINF;

    #pragma unroll
    for (int r = 0; r < ROWS; ++r) {
        const int base = (row0 + r) * NN + j;
        int4   a4 = *reinterpret_cast<const int4*>(adj + base);
        float4 t4 = *reinterpret_cast<const float4*>(tsm + base);
        const int   av[4] = {a4.x, a4.y, a4.z, a4.w};
        const float tv[4] = {t4.x, t4.y, t4.z, t4.w};
        #pragma unroll
        for (int q = 0; q < 4; ++q) {
            float e0 = srcv[r] + dv[q] + cheb_eval(cc, tv[q]);
            e0 = e0 > 0.f ? e0 : LEAK * e0;
            e0 = (av[q] > 0) ? e0 : NEGINF;
            ev[r][q] = e0;
            rmax[r] = fmaxf(rmax[r], e0);
        }
    }

    // ---- block max --------------------------------------------------------
    #pragma unroll
    for (int r = 0; r < ROWS; ++r) {
        float v = rmax[r];
        #pragma unroll
        for (int off = 32; off >= 1; off >>= 1) v = fmaxf(v, __shfl_xor(v, off, 64));
        if ((tid & 63) == 0) wredm[wid][r] = v;
    }
    __syncthreads();
    float m[ROWS];
    #pragma unroll
    for (int r = 0; r < ROWS; ++r) {
        float v = wredm[0][r];
        #pragma unroll
        for (int w = 1; w < 8; ++w) v = fmaxf(v, wredm[w][r]);
        m[r] = v;
    }

    // ---- exp + block sum --------------------------------------------------
    float rs[ROWS];
    #pragma unroll
    for (int r = 0; r < ROWS; ++r) {
        float s0 = 0.f;
        #pragma unroll
        for (int q = 0; q < 4; ++q) {
            float p = __expf(ev[r][q] - m[r]);
            ev[r][q] = p;
            s0 += p;
        }
        #pragma unroll
        for (int off = 32; off >= 1; off >>= 1) s0 += __shfl_xor(s0, off, 64);
        if ((tid & 63) == 0) wreds[wid][r] = s0;
        rs[r] = 0.f;
    }
    __syncthreads();
    #pragma unroll
    for (int r = 0; r < ROWS; ++r) {
        float v = 0.f;
        #pragma unroll
        for (int w = 0; w < 8; ++w) v += wreds[w][r];
        rs[r] = 1.0f / v;
    }

    // ---- write normalized p (fp16) ---------------------------------------
    #pragma unroll
    for (int r = 0; r < ROWS; ++r) {
        H4 u;
        u.h2[0] = __floats2half2_rn(ev[r][0] * rs[r], ev[r][1] * rs[r]);
        u.h2[1] = __floats2half2_rn(ev[r][2] * rs[r], ev[r][3] * rs[r]);
        *reinterpret_cast<float2*>(&lg[r][j]) = u.f2;
    }
    __syncthreads();

    // ---- phase 2: acc[r][k] = sum_j p[r][j] * z[j][k] ---------------------
    const int kq = tid & 7, g = tid >> 3;     // g in 0..63
    const float4* z4 = reinterpret_cast<const float4*>(z);
    float4 acc[ROWS];
    #pragma unroll
    for (int r = 0; r < ROWS; ++r) acc[r] = make_float4(0.f, 0.f, 0.f, 0.f);

    #pragma unroll 2
    for (int jj = 0; jj < 8; ++jj) {
        const int j0 = jj * 256 + g * 4;
        float p[ROWS][4];
        #pragma unroll
        for (int r = 0; r < ROWS; ++r) {
            H4 u;
            u.f2 = *reinterpret_cast<const float2*>(&lg[r][j0]);
            float2 lo = __half22float2(u.h2[0]);
            float2 hi = __half22float2(u.h2[1]);
            p[r][0] = lo.x; p[r][1] = lo.y; p[r][2] = hi.x; p[r][3] = hi.y;
        }
        #pragma unroll
        for (int i = 0; i < 4; ++i) {
            float4 zv = z4[(j0 + i) * (ODIM / 4) + kq];
            #pragma unroll
            for (int r = 0; r < ROWS; ++r) {
                acc[r].x = fmaf(p[r][i], zv.x, acc[r].x);
                acc[r].y = fmaf(p[r][i], zv.y, acc[r].y);
                acc[r].z = fmaf(p[r][i], zv.z, acc[r].z);
                acc[r].w = fmaf(p[r][i], zv.w, acc[r].w);
            }
        }
    }

    // reduce over the 8 g-groups within each wave (lane bits 3,4,5)
    #pragma unroll
    for (int r = 0; r < ROWS; ++r) {
        #pragma unroll
        for (int off = 8; off <= 32; off <<= 1) {
            acc[r].x += __shfl_xor(acc[r].x, off, 64);
            acc[r].y += __shfl_xor(acc[r].y, off, 64);
            acc[r].z += __shfl_xor(acc[r].z, off, 64);
            acc[r].w += __shfl_xor(acc[r].w, off, 64);
        }
    }
    if ((tid & 63) < 8) {
        #pragma unroll
        for (int r = 0; r < ROWS; ++r)
            *reinterpret_cast<float4*>(&part[wid][r][kq * 4]) = acc[r];
    }
    __syncthreads();

    // ---- epilogue: temp = att@z + z, LayerNorm ----------------------------
    if (tid < ROWS * ODIM) {
        const int r = tid >> 5, kk = tid & 31;
        float tot = 0.f;
        #pragma unroll
        for (int w = 0; w < 8; ++w) tot += part[w][r][kk];
        float temp = tot + zi[r][kk];

        float mu = temp;
        #pragma unroll
        for (int off = 16; off >= 1; off >>= 1) mu += __shfl_xor(mu, off, 32);
        mu *= (1.0f / 32.0f);
        float d = temp - mu;
        float v2 = d * d;
        #pragma unroll
        for (int off = 16; off >= 1; off >>= 1) v2 += __shfl_xor(v2, off, 32);
        v2 *= (1.0f / 32.0f);
        float y = d * rsqrtf(v2 + LNEPS) * gam[kk] + bet[kk];
        out[(row0 + r) * ODIM + kk] = y;
    }
}

// ---------------------------------------------------------------------------
extern "C" void kernel_launch(void* const* d_in, const int* in_sizes, int n_in,
                              void* d_out, int out_size, void* d_ws, size_t ws_size,
                              hipStream_t stream)
{
    const float* ini = (const float*)d_in[0];
    const int*   adj = (const int*)  d_in[1];
    const float* tsm = (const float*)d_in[2];
    const float* a   = (const float*)d_in[3];
    const int*   te  = (const int*)  d_in[4];
    const float* W   = (const float*)d_in[5];
    const float* bfq = (const float*)d_in[6];
    const float* gam = (const float*)d_in[7];
    const float* bet = (const float*)d_in[8];
    float* ws  = (float*)d_ws;
    float* out = (float*)d_out;

    k_z<<<NN / 8, 256, 0, stream>>>(ini, a, W, bfq, te, ws);
    k_main<<<NN / ROWS, BLK, 0, stream>>>(adj, tsm, ws, gam, bet, out);
}